// Round 8
// baseline (75.838 us; speedup 1.0000x reference)
//
#include <hip/hip_runtime.h>
#include <math.h>

#define BATCH 32
#define PTS   64
#define NPHI  8192

typedef float v2f __attribute__((ext_vector_type(2)));

// ---------- fp64-core sincos (phi only, precompute kernel) ----------
// Validated bit-faithful to numpy/JAX fp32 trig in rounds 3-7. q0/q1 feed
// every edge with pole-amplified sensitivity (sin phi near 1: ulp 6e-8),
// so phi's trig must stay at fp64 accuracy.
__device__ __forceinline__ void sincosf_f64(float xf, float* s, float* c) {
    const double PIO2_HI = 1.57079632679489661923e+00;
    const double PIO2_LO = 6.12323399573676603587e-17;

    const float kf = __builtin_rintf(__fmul_rn(xf, 0.63661977236758138243f));
    const int   qi = (int)kf;
    const double kd = (double)kf;
    const double x  = (double)xf;

    double r = __builtin_fma(-kd, PIO2_HI, x);
    r = __builtin_fma(-kd, PIO2_LO, r);
    const double r2 = r * r;

    double ps = -2.50507602534068634195e-08;
    ps = __builtin_fma(ps, r2,  2.75573137070700676789e-06);
    ps = __builtin_fma(ps, r2, -1.98412698298579493134e-04);
    ps = __builtin_fma(ps, r2,  8.33333333332248946124e-03);
    ps = __builtin_fma(ps, r2, -1.66666666666666324348e-01);
    const double sinr = __builtin_fma(r * r2, ps, r);

    double pc =  2.08757232129817482790e-09;
    pc = __builtin_fma(pc, r2, -2.75573143513906633035e-07);
    pc = __builtin_fma(pc, r2,  2.48015872894767294178e-05);
    pc = __builtin_fma(pc, r2, -1.38888888888741095749e-03);
    pc = __builtin_fma(pc, r2,  4.16666666666666019037e-02);
    const double cosr = __builtin_fma(r2 * r2, pc, __builtin_fma(-0.5, r2, 1.0));

    const float sf = (float)sinr, cf = (float)cosr;
    const bool sw = (qi & 1);
    const float ss = sw ? cf : sf;
    const float cc = sw ? sf : cf;
    *s = (qi & 2)       ? -ss : ss;
    *c = ((qi + 1) & 2) ? -cc : cc;
}

// Precompute per-phi (q0, q1, scale) — once per launch, 8192 threads.
__global__ __launch_bounds__(256) void phi_table_kernel(
    const float* __restrict__ phi, float4* __restrict__ qtab) {
    const int n = blockIdx.x * 256 + threadIdx.x;
    float sph, cph;
    sincosf_f64(phi[n], &sph, &cph);
    const float q0 = cph;
    const float q1 = __fsub_rn(sph, 1.0f);
    const float scale =
        1.0f / fabsf(__fadd_rn(__fmul_rn(q0, q0), __fmul_rn(q1, q1)));
    qtab[n] = make_float4(q0, q1, scale, 0.0f);
}

// ---------- packed fp32 sincos for edge args (|x| <= ~30) ----------
// Identical arithmetic to round 7's scalar sincosf_f32 (same coeffs, same
// op order — validated absmax 0.199), but sin/cos poly chains packed into
// one float2 chain -> v_pk_fma_f32 halves the issued FMA count.
// Error structure (round-6/7 analysis): high-amplification edges (scale
// large) have tiny args (kf=0, exact reduction, poly ~exact in abs terms);
// kf!=0 only where scale <= ~40 so few-ulp dev stays ~1e-2 after
// amplification.
__device__ __forceinline__ v2f sincos2_f32(float x) {
    const float C1 = 1.5707969665527344f;    // exact-product reduction const
    const float C2 = -6.3975783777e-7f;      // pi/2 - C1

    const float kf = __builtin_rintf(x * 0.63661977236758f);
    const int   qi = (int)kf;
    const float r1 = __builtin_fmaf(-kf, C1, x);   // exact
    const float r  = __builtin_fmaf(-kf, C2, r1);
    const float r2 = r * r;

    const v2f rr = (v2f){r2, r2};
    v2f p = (v2f){2.75573137e-06f, -2.75573144e-07f};            // {S4, C4}
    p = __builtin_elementwise_fma(p, rr, (v2f){-1.98412698e-04f, 2.48015873e-05f});
    p = __builtin_elementwise_fma(p, rr, (v2f){ 8.33333333e-03f, -1.38888889e-03f});
    p = __builtin_elementwise_fma(p, rr, (v2f){-1.66666667e-01f, 4.16666667e-02f});
    // sin tail: fma(r*r2, ps, r); cos tail: fma(r2*r2, pc, 1 - 0.5*r2)
    const v2f a = (v2f){r * r2, r2 * r2};
    const v2f bt = (v2f){r, __builtin_fmaf(-0.5f, r2, 1.0f)};
    const v2f sc = __builtin_elementwise_fma(a, p, bt);          // {sin r, cos r}

    const bool sw = (qi & 1);
    float ss = sw ? sc.y : sc.x;
    float cc = sw ? sc.x : sc.y;
    ss = (qi & 2)       ? -ss : ss;
    cc = ((qi + 1) & 2) ? -cc : cc;
    return (v2f){ss, cc};   // {sin x, cos x}
}

// 256 threads = 128 phi x 2 edge-halves (h = tid&1 does edges [32h, 32h+32)).
// Grid = 2048 blocks -> 8 blocks/CU = 32 waves/CU.
//
// Rounding-faithfulness contract (rounds 3-7): dp/dx/dy/ddq/ddqc/mask exact
// fp32 in numpy's op order (q0/q1 bit-match via fp64-core table) -> the
// 1e-4 branch decision is bit-exact. Post-cancellation math (rcp, fp32
// accum, scale hoisted) has few-ulp freedom (linear sensitivity only).
__global__ __launch_bounds__(256, 8) void scatter_polygon_kernel(
    const float* __restrict__ points,   // [B, P, 2]
    const float4* __restrict__ qtab,    // [N] (q0, q1, scale, -)
    float* __restrict__ out)            // [B, 2, N]
{
    __shared__ float2 spts[PTS];

    const int b = blockIdx.y;
    const int tid = threadIdx.x;
    const int h = tid & 1;
    const int n = blockIdx.x * 128 + (tid >> 1);

    if (tid < PTS) {
        spts[tid] = reinterpret_cast<const float2*>(points)[b * PTS + tid];
    }
    __syncthreads();

    const float4 qv = qtab[n];
    const float q0 = qv.x, q1 = qv.y, scale = qv.z;
    const float nq1 = -q1;

    const int p0i = h ? (PTS / 2 - 1) : (PTS - 1);   // prev vertex (roll by 1)
    float2 pv = spts[p0i];
    float xp = pv.x, yp = pv.y;
    const float dp_prev = __fadd_rn(__fmul_rn(xp, q0), __fmul_rn(yp, q1));
    v2f sc0 = sincos2_f32(dp_prev);                  // {s0, c0}

    v2f acc = (v2f){0.0f, 0.0f};                     // {accI, accR}
    const int pbase = h * (PTS / 2);

    #pragma unroll 8
    for (int i = 0; i < PTS / 2; ++i) {
        const float2 v = spts[pbase + i];
        // dp1q (einsum order, each product rounded to fp32) — exact fp32
        const float dp = __fadd_rn(__fmul_rn(v.x, q0), __fmul_rn(v.y, q1));
        const v2f sc1 = sincos2_f32(dp);             // {s1, c1}

        const float dx = __fsub_rn(v.x, xp);
        const float dy = __fsub_rn(v.y, yp);
        const float ddq  = __fadd_rn(__fmul_rn(dx, q0),  __fmul_rn(dy, q1));
        const float ddqc = __fadd_rn(__fmul_rn(dx, nq1), __fmul_rn(dy, q0));

        const bool  m1  = (fabsf(ddq) >= 1e-4f);     // bit-exact mask
        const float inv = __builtin_amdgcn_rcpf(ddq);// junk if !m1, discarded
        // packed {I, R}: d = sc0 - sc1 = {s0-s1, c0-c1} (exact fp32 subs)
        const v2f d = sc0 - sc1;
        v2f g;
        g.x = m1 ? (d.x * inv) : (-sc0.y);           // gI: (s0-s1)/ddq | -c0
        g.y = m1 ? (d.y * inv) : ( sc0.x);           // gR: (c0-c1)/ddq |  s0
        acc = __builtin_elementwise_fma((v2f){ddqc, ddqc}, g, acc);

        xp = v.x; yp = v.y; sc0 = sc1;
    }

    // combine the two edge-halves (partner lane differs only in bit 0)
    const float totR = scale * (acc.y + __shfl_xor(acc.y, 1));
    const float totI = scale * (acc.x + __shfl_xor(acc.x, 1));

    if (h == 0) {
        out[(size_t)b * 2 * NPHI + n]        = totR;  // real
        out[(size_t)b * 2 * NPHI + NPHI + n] = totI;  // imag
    }
}

extern "C" void kernel_launch(void* const* d_in, const int* in_sizes, int n_in,
                              void* d_out, int out_size, void* d_ws, size_t ws_size,
                              hipStream_t stream) {
    const float* points = (const float*)d_in[0];  // [32, 64, 2] fp32
    const float* phi    = (const float*)d_in[1];  // [8192] fp32
    float* out          = (float*)d_out;          // [32, 2, 8192] fp32
    float4* qtab        = (float4*)d_ws;          // [8192] precomputed q-table

    phi_table_kernel<<<NPHI / 256, 256, 0, stream>>>(phi, qtab);

    dim3 grid(NPHI / 128, BATCH);  // 64 x 32 = 2048 blocks, 8 blocks/CU
    scatter_polygon_kernel<<<grid, 256, 0, stream>>>(points, qtab, out);
}

// Round 9
// 75.762 us; speedup vs baseline: 1.0010x; 1.0010x over previous
//
#include <hip/hip_runtime.h>
#include <math.h>

#define BATCH 32
#define PTS   64
#define NPHI  8192

// ---------- fp64-core sincos (phi only — once per thread) ----------
// Validated bit-faithful to numpy/JAX fp32 trig in rounds 3-8. q0/q1 feed
// every edge with pole-amplified sensitivity (sin phi near 1: ulp 6e-8),
// so phi's trig must stay at fp64 accuracy.
__device__ __forceinline__ void sincosf_f64(float xf, float* s, float* c) {
    const double PIO2_HI = 1.57079632679489661923e+00;
    const double PIO2_LO = 6.12323399573676603587e-17;

    const float kf = __builtin_rintf(__fmul_rn(xf, 0.63661977236758138243f));
    const int   qi = (int)kf;
    const double kd = (double)kf;
    const double x  = (double)xf;

    double r = __builtin_fma(-kd, PIO2_HI, x);
    r = __builtin_fma(-kd, PIO2_LO, r);
    const double r2 = r * r;

    double ps = -2.50507602534068634195e-08;
    ps = __builtin_fma(ps, r2,  2.75573137070700676789e-06);
    ps = __builtin_fma(ps, r2, -1.98412698298579493134e-04);
    ps = __builtin_fma(ps, r2,  8.33333333332248946124e-03);
    ps = __builtin_fma(ps, r2, -1.66666666666666324348e-01);
    const double sinr = __builtin_fma(r * r2, ps, r);

    double pc =  2.08757232129817482790e-09;
    pc = __builtin_fma(pc, r2, -2.75573143513906633035e-07);
    pc = __builtin_fma(pc, r2,  2.48015872894767294178e-05);
    pc = __builtin_fma(pc, r2, -1.38888888888741095749e-03);
    pc = __builtin_fma(pc, r2,  4.16666666666666019037e-02);
    const double cosr = __builtin_fma(r2 * r2, pc, __builtin_fma(-0.5, r2, 1.0));

    const float sf = (float)sinr, cf = (float)cosr;
    const bool sw = (qi & 1);
    const float ss = sw ? cf : sf;
    const float cc = sw ? sf : cf;
    *s = (qi & 2)       ? -ss : ss;
    *c = ((qi + 1) & 2) ? -cc : cc;
}

// ---------- fp32 sincos for edge args (|x| <= ~30) ----------
// Round-7-validated (absmax 0.199). Error structure: high-amplification
// edges (scale large, phi near pi/2) have tiny args -> kf=0, exact
// reduction, compensated cos (1+u) keeps pre-rounding dev ~1e-13 ->
// fp32-rounded bits match numpy's. kf!=0 only where scale <= ~40, so
// few-ulp dev stays ~1e-2 after amplification.
__device__ __forceinline__ void sincosf_f32(float x, float* s, float* c) {
    const float C1 = 1.5707969665527344f;    // exact-product reduction const
    const float C2 = -6.3975783777e-7f;      // pi/2 - C1

    const float kf = __builtin_rintf(x * 0.63661977236758f);
    const int   qi = (int)kf;
    const float r1 = __builtin_fmaf(-kf, C1, x);   // exact
    const float r  = __builtin_fmaf(-kf, C2, r1);
    const float r2 = r * r;

    float ps = __builtin_fmaf(2.75573137e-06f, r2, -1.98412698e-04f);
    ps = __builtin_fmaf(ps, r2,  8.33333333e-03f);
    ps = __builtin_fmaf(ps, r2, -1.66666667e-01f);
    const float sr = __builtin_fmaf(r * r2, ps, r);

    float pc = __builtin_fmaf(-2.75573144e-07f, r2, 2.48015873e-05f);
    pc = __builtin_fmaf(pc, r2, -1.38888889e-03f);
    pc = __builtin_fmaf(pc, r2,  4.16666667e-02f);
    const float u  = __builtin_fmaf(r2 * r2, pc, -(0.5f * r2));
    const float cr = 1.0f + u;

    const bool sw = (qi & 1);
    const float ss = sw ? cr : sr;
    const float cc = sw ? sr : cr;
    *s = (qi & 2)       ? -ss : ss;
    *c = ((qi + 1) & 2) ? -cc : cc;
}

// One thread per (b, n), ALL 64 edges. Vertex data is block-uniform
// (same b for the whole block) and read through a uniform pointer in
// uniform control flow -> the compiler scalarizes these to s_load
// (SGPR operands): no LDS, no ds_read lgkm stalls, no __syncthreads,
// no h-split combine. 1024 blocks -> 4 blocks/CU = 16 waves/CU; R4->R5
// showed occupancy beyond 4 waves/SIMD adds little (issue-bound), and
// __launch_bounds__(256,4) gives the allocator 128 VGPRs for ILP.
//
// Rounding-faithfulness contract (rounds 3-8): dp/dx/dy/ddq/ddqc/mask are
// exact fp32 in numpy's op order (q0/q1 fp64-core accurate) -> the 1e-4
// branch decision is bit-exact. Post-cancellation math (rcp, fp32 accum,
// scale hoisted out of the sum) has few-ulp freedom (linear sensitivity).
__global__ __launch_bounds__(256, 4) void scatter_polygon_kernel(
    const float* __restrict__ points,   // [B, P, 2]
    const float* __restrict__ phi,      // [N]
    float* __restrict__ out)            // [B, 2, N]
{
    const int b = blockIdx.y;
    const int n = blockIdx.x * 256 + threadIdx.x;
    const float* __restrict__ pb = points + b * 2 * PTS;  // block-uniform base

    const float ph = phi[n];
    float sph, cph;
    sincosf_f64(ph, &sph, &cph);                // fp64 core: q must bit-match
    const float q0  = cph;
    const float q1  = __fsub_rn(sph, 1.0f);
    const float nq1 = -q1;
    const float scale =
        1.0f / fabsf(__fadd_rn(__fmul_rn(q0, q0), __fmul_rn(q1, q1)));

    // previous vertex = points[b, P-1] (roll by 1) — uniform load
    float xp = pb[2 * (PTS - 1)];
    float yp = pb[2 * (PTS - 1) + 1];
    const float dp_prev = __fadd_rn(__fmul_rn(xp, q0), __fmul_rn(yp, q1));
    float s0, c0;
    sincosf_f32(dp_prev, &s0, &c0);

    float accR = 0.0f, accI = 0.0f;

    #pragma unroll 8
    for (int p = 0; p < PTS; ++p) {
        const float x = pb[2 * p];              // uniform -> s_load
        const float y = pb[2 * p + 1];
        // dp1q (einsum order, each product rounded to fp32) — exact fp32
        const float dp = __fadd_rn(__fmul_rn(x, q0), __fmul_rn(y, q1));
        float s1, c1;
        sincosf_f32(dp, &s1, &c1);

        const float dx = __fsub_rn(x, xp);
        const float dy = __fsub_rn(y, yp);
        const float ddq  = __fadd_rn(__fmul_rn(dx, q0),  __fmul_rn(dy, q1));
        const float ddqc = __fadd_rn(__fmul_rn(dx, nq1), __fmul_rn(dy, q0));

        const bool  m1  = (fabsf(ddq) >= 1e-4f);      // bit-exact mask
        const float inv = __builtin_amdgcn_rcpf(ddq); // junk if !m1, discarded
        const float dR = __fsub_rn(c0, c1);           // case1 numerators
        const float dI = __fsub_rn(s0, s1);
        const float gR = m1 ? (dR * inv) : s0;        // case2: (s0, -c0)
        const float gI = m1 ? (dI * inv) : (-c0);
        accR = __builtin_fmaf(ddqc, gR, accR);
        accI = __builtin_fmaf(ddqc, gI, accI);

        xp = x; yp = y; c0 = c1; s0 = s1;
    }

    out[(size_t)b * 2 * NPHI + n]        = scale * accR;  // real
    out[(size_t)b * 2 * NPHI + NPHI + n] = scale * accI;  // imag
}

extern "C" void kernel_launch(void* const* d_in, const int* in_sizes, int n_in,
                              void* d_out, int out_size, void* d_ws, size_t ws_size,
                              hipStream_t stream) {
    const float* points = (const float*)d_in[0];  // [32, 64, 2] fp32
    const float* phi    = (const float*)d_in[1];  // [8192] fp32
    float* out          = (float*)d_out;          // [32, 2, 8192] fp32

    dim3 grid(NPHI / 256, BATCH);  // 32 x 32 = 1024 blocks, 4 blocks/CU
    scatter_polygon_kernel<<<grid, 256, 0, stream>>>(points, phi, out);
}